// Round 1
// baseline (245.116 us; speedup 1.0000x reference)
//
#include <hip/hip_runtime.h>

// CovLayer: X [B=64, C=256, T=2048] fp32 -> cov [B, 256, 256] fp32
// cov[b,c,d] = (1/T) * sum_t X[b,c,t]X[b,d,t] - mu[b,c]*mu[b,d]   (E[xy]-mu*mu form)
// Single fused kernel: bf16 MFMA Gram matrix + MFMA ones-trick row/col sums.
// No workspace used.

#define NB 64
#define NC 256
#define NT 2048

typedef __bf16 bf16x8 __attribute__((ext_vector_type(8)));
typedef float  f32x8  __attribute__((ext_vector_type(8)));
typedef float  f32x4  __attribute__((ext_vector_type(4)));

__global__ __launch_bounds__(256) void cov_mfma_kernel(const float* __restrict__ X,
                                                       float* __restrict__ out) {
    // XCD-aware decode: the 4 tiles of a batch share (bid & 7) -> same XCD L2.
    const int bid  = blockIdx.x;
    const int xcd  = bid & 7;
    const int s    = bid >> 3;         // 0..31
    const int tile = s & 3;            // 2x2 tile of the 256x256 output
    const int b    = xcd + 8 * (s >> 2);
    const int tm   = tile >> 1, tn = tile & 1;
    const int row0 = tm * 128, col0 = tn * 128;

    const float* __restrict__ Xb = X + (size_t)b * (NC * NT);

    __shared__ __bf16 sA[128 * 32];    // [row][k], 64B rows
    __shared__ __bf16 sB[128 * 32];

    const int t    = threadIdx.x;      // 256 threads = 4 waves
    const int lane = t & 63;
    const int wave = t >> 6;
    const int wm   = wave >> 1, wn = wave & 1;   // 2x2 waves, 64x64 each
    const int quad = lane >> 4;
    const int l16  = lane & 15;

    // Staging: thread t owns (row = t>>2, 8-col chunk = t&3) and the row+64 twin.
    const int srow = t >> 2;
    const int sch  = t & 3;

    const float* gA0 = Xb + (size_t)(row0 + srow)      * NT + sch * 8;
    const float* gA1 = Xb + (size_t)(row0 + srow + 64) * NT + sch * 8;
    const float* gB0 = Xb + (size_t)(col0 + srow)      * NT + sch * 8;
    const float* gB1 = Xb + (size_t)(col0 + srow + 64) * NT + sch * 8;

    // LDS dest: element offset idx*8 == (idx>>2)*32 + (idx&3)*8  (contiguous 16B/thread)
    __bf16* lA0 = &sA[t * 8];
    __bf16* lA1 = &sA[t * 8 + 2048];
    __bf16* lB0 = &sB[t * 8];
    __bf16* lB1 = &sB[t * 8 + 2048];

    f32x4 acc[4][4];
    f32x4 accRS[4];   // row sums of A sub-tiles  (mfma(aF, ones))
    f32x4 accCS[4];   // col sums (= row sums of B rows)  (mfma(ones, bF))
#pragma unroll
    for (int i = 0; i < 4; ++i) {
        accRS[i] = (f32x4){0.f, 0.f, 0.f, 0.f};
        accCS[i] = (f32x4){0.f, 0.f, 0.f, 0.f};
#pragma unroll
        for (int j = 0; j < 4; ++j) acc[i][j] = (f32x4){0.f, 0.f, 0.f, 0.f};
    }

    const bf16x8 ones = {(__bf16)1.0f, (__bf16)1.0f, (__bf16)1.0f, (__bf16)1.0f,
                         (__bf16)1.0f, (__bf16)1.0f, (__bf16)1.0f, (__bf16)1.0f};

    for (int kk = 0; kk < NT; kk += 32) {
        // Global loads + convert before the barrier: overlaps previous MFMA burst.
        f32x8 vA0 = *(const f32x8*)(gA0 + kk);
        f32x8 vA1 = *(const f32x8*)(gA1 + kk);
        f32x8 vB0 = *(const f32x8*)(gB0 + kk);
        f32x8 vB1 = *(const f32x8*)(gB1 + kk);
        bf16x8 hA0 = __builtin_convertvector(vA0, bf16x8);
        bf16x8 hA1 = __builtin_convertvector(vA1, bf16x8);
        bf16x8 hB0 = __builtin_convertvector(vB0, bf16x8);
        bf16x8 hB1 = __builtin_convertvector(vB1, bf16x8);

        __syncthreads();               // previous iteration's frag reads done
        *(bf16x8*)lA0 = hA0;
        *(bf16x8*)lA1 = hA1;
        *(bf16x8*)lB0 = hB0;
        *(bf16x8*)lB1 = hB1;
        __syncthreads();               // staging visible

        bf16x8 aF[4], bF[4];
#pragma unroll
        for (int mt = 0; mt < 4; ++mt)
            aF[mt] = *(const bf16x8*)&sA[(wm * 64 + mt * 16 + l16) * 32 + quad * 8];
#pragma unroll
        for (int nt = 0; nt < 4; ++nt)
            bF[nt] = *(const bf16x8*)&sB[(wn * 64 + nt * 16 + l16) * 32 + quad * 8];

#pragma unroll
        for (int mt = 0; mt < 4; ++mt) {
            accRS[mt] = __builtin_amdgcn_mfma_f32_16x16x32_bf16(aF[mt], ones, accRS[mt], 0, 0, 0);
#pragma unroll
            for (int nt = 0; nt < 4; ++nt)
                acc[mt][nt] = __builtin_amdgcn_mfma_f32_16x16x32_bf16(aF[mt], bF[nt], acc[mt][nt], 0, 0, 0);
        }
#pragma unroll
        for (int nt = 0; nt < 4; ++nt)
            accCS[nt] = __builtin_amdgcn_mfma_f32_16x16x32_bf16(ones, bF[nt], accCS[nt], 0, 0, 0);
    }

    // Epilogue: C/D layout (16x16): col = lane&15, row = quad*4 + reg.
    // accRS[mt][r] holds rowsum of exactly the row this lane writes (m = quad*4+r).
    // accCS[nt][0] holds colsum of this lane's column (n = l16), any reg.
    const float invT = 1.0f / NT;
    float* __restrict__ outB = out + (size_t)b * (NC * NC);
#pragma unroll
    for (int nt = 0; nt < 4; ++nt) {
        const int col = col0 + wn * 64 + nt * 16 + l16;
        const float muc = accCS[nt][0] * invT;
#pragma unroll
        for (int mt = 0; mt < 4; ++mt) {
            const int rbase = row0 + wm * 64 + mt * 16 + quad * 4;
#pragma unroll
            for (int r = 0; r < 4; ++r) {
                const float mur = accRS[mt][r] * invT;
                outB[(size_t)(rbase + r) * NC + col] = acc[mt][nt][r] * invT - mur * muc;
            }
        }
    }
}

extern "C" void kernel_launch(void* const* d_in, const int* in_sizes, int n_in,
                              void* d_out, int out_size, void* d_ws, size_t ws_size,
                              hipStream_t stream) {
    const float* X = (const float*)d_in[0];
    float* out = (float*)d_out;
    (void)in_sizes; (void)n_in; (void)out_size; (void)d_ws; (void)ws_size;
    cov_mfma_kernel<<<NB * 4, 256, 0, stream>>>(X, out);
}

// Round 2
// 218.926 us; speedup vs baseline: 1.1196x; 1.1196x over previous
//
#include <hip/hip_runtime.h>

// CovLayer: X [B=64, C=256, T=2048] fp32 -> cov [B, 256, 256] fp32
// cov[b,c,d] = (1/T) * sum_t X[b,c,t]X[b,d,t] - mu[b,c]*mu[b,d]
// Round 2: 64x64 tiles -> 1024 blocks (4 blocks/CU, 16 waves/CU vs 4 before),
// explicit global-load prefetch pipeline, LDS stride 40 (2-way conflicts only).

#define NB 64
#define NC 256
#define NT 2048
#define LSTR 40   // LDS row stride in bf16 elements (32 data + 8 pad)

typedef __bf16 bf16x8 __attribute__((ext_vector_type(8)));
typedef float  f32x8  __attribute__((ext_vector_type(8)));
typedef float  f32x4  __attribute__((ext_vector_type(4)));

__global__ __launch_bounds__(256) void cov_mfma_kernel(const float* __restrict__ X,
                                                       float* __restrict__ out) {
    // 1024 blocks. Same batch -> same XCD (L2 locality for the batch's 2 MB).
    const int bid  = blockIdx.x;
    const int xcd  = bid & 7;
    const int s    = bid >> 3;         // 0..127
    const int tile = s & 15;           // 4x4 grid of 64x64 tiles
    const int b    = xcd + 8 * (s >> 4);
    const int tm   = tile >> 2, tn = tile & 3;
    const int row0 = tm * 64, col0 = tn * 64;

    const float* __restrict__ Xb = X + (size_t)b * (NC * NT);

    __shared__ __bf16 sA[64 * LSTR];   // 5 KB
    __shared__ __bf16 sB[64 * LSTR];

    const int t    = threadIdx.x;      // 256 threads = 4 waves
    const int lane = t & 63;
    const int wave = t >> 6;
    const int wm   = wave >> 1, wn = wave & 1;   // 2x2 waves, 32x32 each
    const int quad = lane >> 4;
    const int l16  = lane & 15;

    // Staging: thread t owns (row = t>>2, 8-col chunk = t&3): one f32x8 each for A and B.
    const int srow = t >> 2;
    const int sch  = t & 3;
    const float* gA = Xb + (size_t)(row0 + srow) * NT + sch * 8;
    const float* gB = Xb + (size_t)(col0 + srow) * NT + sch * 8;
    __bf16* lA = &sA[srow * LSTR + sch * 8];
    __bf16* lB = &sB[srow * LSTR + sch * 8];

    f32x4 acc[2][2];
    f32x4 accRS[2];   // row sums via mfma(aF, ones) — lands in C-layout rows this lane writes
    f32x4 accCS[2];   // col sums via mfma(ones, bF) — col at lane&15
#pragma unroll
    for (int i = 0; i < 2; ++i) {
        accRS[i] = (f32x4){0.f, 0.f, 0.f, 0.f};
        accCS[i] = (f32x4){0.f, 0.f, 0.f, 0.f};
#pragma unroll
        for (int j = 0; j < 2; ++j) acc[i][j] = (f32x4){0.f, 0.f, 0.f, 0.f};
    }

    const bf16x8 ones = {(__bf16)1.0f, (__bf16)1.0f, (__bf16)1.0f, (__bf16)1.0f,
                         (__bf16)1.0f, (__bf16)1.0f, (__bf16)1.0f, (__bf16)1.0f};

    // Prefetch iteration 0.
    f32x8 vA = *(const f32x8*)gA;
    f32x8 vB = *(const f32x8*)gB;

    for (int kk = 0; kk < NT; kk += 32) {
        bf16x8 hA = __builtin_convertvector(vA, bf16x8);
        bf16x8 hB = __builtin_convertvector(vB, bf16x8);

        __syncthreads();               // previous iteration's frag reads done
        *(bf16x8*)lA = hA;
        *(bf16x8*)lB = hB;
        __syncthreads();               // staging visible

        // Issue next iteration's loads now: ~900-cycle HBM latency overlaps the
        // frag reads + MFMA burst below instead of stalling the next convert.
        if (kk + 32 < NT) {
            vA = *(const f32x8*)(gA + kk + 32);
            vB = *(const f32x8*)(gB + kk + 32);
        }

        bf16x8 aF[2], bF[2];
#pragma unroll
        for (int mt = 0; mt < 2; ++mt)
            aF[mt] = *(const bf16x8*)&sA[(wm * 32 + mt * 16 + l16) * LSTR + quad * 8];
#pragma unroll
        for (int nt = 0; nt < 2; ++nt)
            bF[nt] = *(const bf16x8*)&sB[(wn * 32 + nt * 16 + l16) * LSTR + quad * 8];

#pragma unroll
        for (int mt = 0; mt < 2; ++mt) {
            accRS[mt] = __builtin_amdgcn_mfma_f32_16x16x32_bf16(aF[mt], ones, accRS[mt], 0, 0, 0);
#pragma unroll
            for (int nt = 0; nt < 2; ++nt)
                acc[mt][nt] = __builtin_amdgcn_mfma_f32_16x16x32_bf16(aF[mt], bF[nt], acc[mt][nt], 0, 0, 0);
        }
#pragma unroll
        for (int nt = 0; nt < 2; ++nt)
            accCS[nt] = __builtin_amdgcn_mfma_f32_16x16x32_bf16(ones, bF[nt], accCS[nt], 0, 0, 0);
    }

    // Epilogue. C/D layout (16x16): col = lane&15, row = quad*4 + reg.
    const float invT = 1.0f / NT;
    float* __restrict__ outB = out + (size_t)b * (NC * NC);
#pragma unroll
    for (int nt = 0; nt < 2; ++nt) {
        const int col = col0 + wn * 32 + nt * 16 + l16;
        const float muc = accCS[nt][0] * invT;
#pragma unroll
        for (int mt = 0; mt < 2; ++mt) {
            const int rbase = row0 + wm * 32 + mt * 16 + quad * 4;
#pragma unroll
            for (int r = 0; r < 4; ++r) {
                const float mur = accRS[mt][r] * invT;
                outB[(size_t)(rbase + r) * NC + col] = acc[mt][nt][r] * invT - mur * muc;
            }
        }
    }
}

extern "C" void kernel_launch(void* const* d_in, const int* in_sizes, int n_in,
                              void* d_out, int out_size, void* d_ws, size_t ws_size,
                              hipStream_t stream) {
    const float* X = (const float*)d_in[0];
    float* out = (float*)d_out;
    (void)in_sizes; (void)n_in; (void)out_size; (void)d_ws; (void)ws_size;
    cov_mfma_kernel<<<NB * 16, 256, 0, stream>>>(X, out);
}